// Round 20
// baseline (188.366 us; speedup 1.0000x reference)
//
#include <hip/hip_runtime.h>

typedef unsigned short u16;
typedef unsigned int u32;
typedef unsigned long long u64;
typedef _Float16 f16x8 __attribute__((ext_vector_type(8)));
typedef float f32x4 __attribute__((ext_vector_type(4)));

__device__ __forceinline__ u16 f2h(float f) {
    _Float16 h = (_Float16)f;
    return __builtin_bit_cast(u16, h);
}

// ---- setup+smd (grid 2834): W3n | conv | W2h | tab | c0 | SMd (taps computed inline) ----
__global__ __launch_bounds__(256) void setup_kernel(
        const float* __restrict__ x, const float* __restrict__ w_red,
        const float* __restrict__ b_red, const float* __restrict__ w3d,
        const float* __restrict__ w2d, const float* __restrict__ b3,
        const float* __restrict__ b2,
        u16* __restrict__ W3n, u16* __restrict__ hT16,
        u16* __restrict__ W2h, int* __restrict__ tab,
        float* __restrict__ c0, u16* __restrict__ SMd) {
#pragma clang fp contract(off)
    __shared__ alignas(16) u16 rows[4][4096];
    int bid = blockIdx.x, tid = threadIdx.x;
    if (bid < 256) {                       // W3n[n][o*128+c] = fp16(w3d[o][c][n])
        int oc = bid * 256 + tid;
        float4 v[8];
        const float4* src = (const float4*)(w3d + (size_t)oc * 32);
#pragma unroll
        for (int j = 0; j < 8; ++j) v[j] = src[j];
        const float* vf = (const float*)v;
#pragma unroll
        for (int n = 0; n < 32; ++n)
            W3n[n * 65536 + oc] = f2h(vf[n]);
        return;
    }
    if (bid < 512) {                       // conv1d+ReLU -> hT16[b][t][c] fp16
        if (tid >= 128) return;
        int idx = bid - 256;
        int co = idx & 127, b = idx >> 7, t = tid;
        float acc = b_red[co];
        const float* xb = x + b * 256 * 128;
        const float* wr = w_red + co * 768;
        for (int ci = 0; ci < 256; ++ci) {
            float w0 = wr[ci * 3 + 0], w1 = wr[ci * 3 + 1], w2 = wr[ci * 3 + 2];
            float x1 = xb[ci * 128 + t];
            float x0 = (t >= 1)   ? xb[ci * 128 + t - 1] : 0.f;
            float x2 = (t < 127) ? xb[ci * 128 + t + 1] : 0.f;
            acc += x0 * w0 + x1 * w1 + x2 * w2;
        }
        hT16[b * 16384 + t * 128 + co] = f2h(fmaxf(acc, 0.f));
        return;
    }
    if (bid < 768) {                       // W2h
        int i = (bid - 512) * 256 + tid;
        W2h[i] = f2h(w2d[i]);
        return;
    }
    if (bid == 768) {                      // cell -> (d,m)
        for (int cell = tid; cell < 8256; cell += 256) {
            int off = 0, d = 0;
            while (d < 128) { int w = 128 - d; if (cell < off + w) break; off += w; ++d; }
            tab[cell] = (d << 8) | (cell - off);
        }
        return;
    }
    if (bid == 769) {                      // c0
        int o2 = tid >> 1, half = tid & 1;
        float s = 0.f;
        const float* row = w2d + o2 * 512 + half * 256;
        for (int o = 0; o < 256; ++o) s += row[o] * fmaxf(b3[half * 256 + o], 0.f);
        s += __shfl_xor(s, 1);
        if (half == 0) c0[o2] = fmaxf(s + b2[o2], 0.f);
        return;
    }
    // ---- SMd branch: 4 cells/block, taps computed inline (bit-exact math, verified) ----
    const int cid = tid >> 6, l = tid & 63;
    const int cell = (bid - 770) * 4 + cid;
    char* rowb = (char*)&rows[cid][0];
    f32x4 z = {0.f, 0.f, 0.f, 0.f};
#pragma unroll
    for (int j = 0; j < 8; ++j)
        *(f32x4*)(rowb + l * 128 + j * 16) = z;
    __syncthreads();
    if (l < 32) {
        int n = l;
        int off = 0, d = 0;
        while (d < 128) { int w = 128 - d; if (cell < off + w) break; off += w; ++d; }
        int m = cell - off;
        double xm = m - (d + 1) * 0.5;
        double step = (2 * d + 1) / 95.0;
        int t0 = (int)floor(xm + step * (double)(3 * n));
        int dnr[3], upr[3]; double av[3], bv[3];
#pragma unroll
        for (int j = 0; j < 3; ++j) {
            double p = step * (double)(3 * n + j);   // mul then add: matches numpy
            double s = xm + p;
            double tr = trunc(s);
            double dec = s - tr;
            int dn = (int)tr, up = (int)ceil(s);
            dnr[j] = dn - t0; upr[j] = up - t0;
            av[j] = (dn >= 0 && dn <= 127) ? (1.0 - dec) * (1.0 / 3.0) : 0.0;
            bv[j] = (up >= 0 && up <= 127) ? dec * (1.0 / 3.0) : 0.0;
        }
#pragma unroll
        for (int sl = 0; sl < 8; ++sl) {   // static composition (no scratch)
            double a = 0.0;
#pragma unroll
            for (int j = 0; j < 3; ++j) {
                a += (dnr[j] == sl) ? av[j] : 0.0;
                a += (upr[j] == sl) ? bv[j] : 0.0;
            }
            int t = t0 + sl;
            if ((unsigned)t < 128u)
                rows[cid][n * 128 + t] = f2h((float)a);
        }
    }
    __syncthreads();
    u16* dst = SMd + (size_t)cell * 4096;
#pragma unroll
    for (int j = 0; j < 8; ++j)
        *(f32x4*)((char*)dst + l * 16 + j * 1024) = *(const f32x4*)(rowb + l * 16 + j * 1024);
}

// ---------------- gkern: G[b][o][n*128+t] = sum_c W3n[n][o][c] * hT16[b][t][c] ----------
__global__ __launch_bounds__(256) void gkern(const u16* __restrict__ W3n,
                                             const u16* __restrict__ hT16,
                                             u16* __restrict__ G) {
    __shared__ alignas(16) u16 As[128 * 128];
    __shared__ alignas(16) u16 Bs[128 * 128];
    const int tid = threadIdx.x;
    const int lane = tid & 63, wv = tid >> 6;
    const int fr = lane & 15, fq = lane >> 4;
    const int bid = blockIdx.x;
    const int b = bid & 1, n = (bid >> 1) & 31, os = bid >> 6;
    const u16* Abase = W3n + n * 65536 + os * 128 * 128;
    const u16* Bbase = hT16 + b * 16384;
#pragma unroll
    for (int i = 0; i < 8; ++i) {
        int off = i * 4096 + tid * 16;
        int row = off >> 8, colb = off & 255;
        int scol = colb ^ ((row & 7) << 4);
        __builtin_amdgcn_global_load_lds(
            (const __attribute__((address_space(1))) void*)(Abase + row * 128 + (scol >> 1)),
            (__attribute__((address_space(3))) void*)((char*)As + off), 16, 0, 0);
        __builtin_amdgcn_global_load_lds(
            (const __attribute__((address_space(1))) void*)(Bbase + row * 128 + (scol >> 1)),
            (__attribute__((address_space(3))) void*)((char*)Bs + off), 16, 0, 0);
    }
    asm volatile("s_waitcnt vmcnt(0)" ::: "memory");
    __syncthreads();
    const int wm = wv >> 1, wn = wv & 1;
    f32x4 acc[4][4] = {};
#pragma unroll
    for (int kk = 0; kk < 4; ++kk) {
        int kb = kk * 64 + fq * 16;
        f16x8 af[4], bf[4];
#pragma unroll
        for (int mf = 0; mf < 4; ++mf) {
            int row = wm * 64 + mf * 16 + fr;
            af[mf] = *(const f16x8*)((const char*)As + row * 256 + (kb ^ ((row & 7) << 4)));
        }
#pragma unroll
        for (int nf = 0; nf < 4; ++nf) {
            int row = wn * 64 + nf * 16 + fr;
            bf[nf] = *(const f16x8*)((const char*)Bs + row * 256 + (kb ^ ((row & 7) << 4)));
        }
#pragma unroll
        for (int mf = 0; mf < 4; ++mf)
#pragma unroll
            for (int nf = 0; nf < 4; ++nf)
                acc[mf][nf] = __builtin_amdgcn_mfma_f32_16x16x32_f16(
                    af[mf], bf[nf], acc[mf][nf], 0, 0, 0);
    }
    u16* Gb = G + (size_t)b * 2097152;
#pragma unroll
    for (int mf = 0; mf < 4; ++mf) {
        int o = os * 128 + wm * 64 + mf * 16 + (fq << 2);
#pragma unroll
        for (int nf = 0; nf < 4; ++nf) {
            int t = wn * 64 + nf * 16 + fr;
            f32x4 v = acc[mf][nf];
#pragma unroll
            for (int r = 0; r < 4; ++r)
                Gb[(size_t)(o + r) * 4096 + n * 128 + t] = f2h(v[r]);
        }
    }
}

// ---------------- GEMM1 v14: BK=32, A+B tribuf 48KB -> 3 blocks/CU, one barrier --------
// A = G[1024][4096], B = SMd[8256][4096]. BM=128, BN=128, BK=32 (128 iters).
// 256 thr, 4 waves (2x2), wave tile 64x64 (acc 4x4). LDS 48KB = A 3x8KB @0 + B 3x8KB
// @24576 -> 3 blocks/CU (12 waves: two other blocks cover each stall). Rows are 64B;
// swizzle (row&3)<<4 (both sides). Schedule = v12's proven rotation: compute buf[t%3] |
// stage(t+2 -> (t+2)%3) | vmcnt(4) [tile t+1 done, t+2 in flight] | single s_barrier.
// Grid 520 = 65 panels x 8 m-splits; p = c*8+(r&7): a panel's splits share an XCD.
__global__ __launch_bounds__(256, 3) void mega_kernel(
        const u16* __restrict__ G, const u16* __restrict__ SMd,
        const float* __restrict__ b3, u16* __restrict__ m3T) {
    __shared__ alignas(16) char lds[49152];

    const int tid = threadIdx.x;
    const int lane = tid & 63, wv = tid >> 6;
    const int fr = lane & 15, fq = lane >> 4;
    const int swz = (fr & 3) << 4;                 // 64B rows: XOR low 2 row bits
    const int wm = wv >> 1, wn = wv & 1;           // 2m x 2n wave grid

    const int id = blockIdx.x;
    int p, s;
    if (id < 512) { int c = id >> 6, r = id & 63; p = c * 8 + (r & 7); s = r >> 3; }
    else          { p = 64; s = id - 512; }
    const int cell0 = p * 128;
    const int cn = (p == 64) ? 64 : 128;
    const int m0 = s * 128;

    f32x4 acc[4][4] = {};

    auto stage = [&](int buf, int kt) {            // 4 global_load_lds per thread
        char* A = lds + buf * 8192;
        char* B = lds + 24576 + buf * 8192;
#pragma unroll
        for (int i2 = 0; i2 < 2; ++i2) {           // A: 128 rows x 64B
            int off = i2 * 4096 + tid * 16;
            int row = off >> 6, colb = off & 63;
            int scol = colb ^ ((row & 3) << 4);
            const u16* ga = G + (size_t)(m0 + row) * 4096 + kt + (scol >> 1);
            __builtin_amdgcn_global_load_lds(
                (const __attribute__((address_space(1))) void*)ga,
                (__attribute__((address_space(3))) void*)(A + off), 16, 0, 0);
        }
#pragma unroll
        for (int i2 = 0; i2 < 2; ++i2) {           // B: 128 rows x 64B
            int off = i2 * 4096 + tid * 16;
            int row = off >> 6, colb = off & 63;
            int r2 = row < cn ? row : 0;
            int scol = colb ^ ((row & 3) << 4);
            const u16* gb = SMd + (size_t)(cell0 + r2) * 4096 + kt + (scol >> 1);
            __builtin_amdgcn_global_load_lds(
                (const __attribute__((address_space(1))) void*)gb,
                (__attribute__((address_space(3))) void*)(B + off), 16, 0, 0);
        }
    };

    stage(0, 0);
    stage(1, 32);
    asm volatile("s_waitcnt vmcnt(4)" ::: "memory");   // tile 0 landed
    __builtin_amdgcn_sched_barrier(0);
    __builtin_amdgcn_s_barrier();
    __builtin_amdgcn_sched_barrier(0);

    int cur = 0;                                   // t % 3
    for (int t = 0; t < 128; ++t) {
        const char* A = lds + cur * 8192;
        const char* Bp = lds + 24576 + cur * 8192;
        const int kb = (fq << 4) ^ swz;
        f16x8 af[4], bfr[4];
#pragma unroll
        for (int mf = 0; mf < 4; ++mf)
            af[mf] = *(const f16x8*)(A + (wm * 64 + mf * 16 + fr) * 64 + kb);
#pragma unroll
        for (int nf = 0; nf < 4; ++nf)
            bfr[nf] = *(const f16x8*)(Bp + (wn * 64 + nf * 16 + fr) * 64 + kb);
        __builtin_amdgcn_s_setprio(1);
#pragma unroll
        for (int mf = 0; mf < 4; ++mf)
#pragma unroll
            for (int nf = 0; nf < 4; ++nf)
                acc[mf][nf] = __builtin_amdgcn_mfma_f32_16x16x32_f16(
                    af[mf], bfr[nf], acc[mf][nf], 0, 0, 0);
        __builtin_amdgcn_s_setprio(0);
        int nxt = cur + 2; if (nxt >= 3) nxt -= 3;            // (t+2) % 3
        if (t < 126) {
            stage(nxt, (t + 2) << 5);
            asm volatile("s_waitcnt vmcnt(4)" ::: "memory");  // tile t+1 landed
        } else {
            asm volatile("s_waitcnt vmcnt(0)" ::: "memory");
        }
        __builtin_amdgcn_sched_barrier(0);
        __builtin_amdgcn_s_barrier();              // the ONLY barrier per iteration
        __builtin_amdgcn_sched_barrier(0);
        cur += 1; if (cur >= 3) cur -= 3;
    }

    // epilogue: m = m0 + wm*64 + mf*16 + fq*4 + r -> (b = m>>9, o = m&511)
#pragma unroll
    for (int mf = 0; mf < 4; ++mf) {
        int m = m0 + wm * 64 + mf * 16 + (fq << 2);
        int b = m >> 9, o = m & 511;
#pragma unroll
        for (int nf = 0; nf < 4; ++nf) {
            int cl = wn * 64 + nf * 16 + fr;
            if (cl < cn) {
                f32x4 v = acc[mf][nf];
                u64 pw = 0;
#pragma unroll
                for (int r = 0; r < 4; ++r) {
                    float z = fmaxf(v[r] + b3[o + r], 0.f);
                    pw |= (u64)f2h(z) << (16 * r);
                }
                *(u64*)(m3T + ((size_t)(b * 8256 + cell0 + cl)) * 512 + o) = pw;
            }
        }
    }
}

// ---------------- GEMM2+fill: one-barrier tribuf GEMM; blocks>=258 fill ----------------
__global__ __launch_bounds__(256, 2) void gemm2f_kernel(const u16* __restrict__ A,
                                                        const u16* __restrict__ B,
                                                        const float* __restrict__ bias,
                                                        const int* __restrict__ tab,
                                                        const float* __restrict__ c0,
                                                        float* __restrict__ out) {
    __shared__ alignas(16) char lds[73728];        // As 3x8KB @0, Bs 3x16KB @24576
    if (blockIdx.x >= 258) {                       // fill part
        int idx = blockIdx.x - 258;                // [0,256)
        int d = idx & 127, b = idx >> 7;
        if (d == 0) return;
        int cnt = d, total = 128 * cnt;
        for (int j = threadIdx.x; j < total; j += blockDim.x) {
            int o2 = j / cnt, m = 128 - cnt + (j % cnt);
            out[((size_t)b << 21) + ((size_t)o2 << 14) + (d << 7) + m] = c0[o2];
        }
        return;
    }
    const int tid = threadIdx.x;
    const int lane = tid & 63, wave = tid >> 6;
    const int m0 = blockIdx.x * 64;
    const int wr = wave & 1, wc = wave >> 1;
    const int fr = lane & 15, fq = lane >> 4;
    const int swz = (fr & 7) << 4;
    f32x4 acc[2][4] = {};

    auto stage = [&](int buf, int kt) {            // 6 loads per thread
        char* As = lds + buf * 8192;
        char* Bs = lds + 24576 + buf * 16384;
#pragma unroll
        for (int i = 0; i < 2; ++i) {              // A: 64 rows x 128B
            int off = i * 4096 + tid * 16;
            int row = off >> 7, colb = off & 127;
            int scol = colb ^ ((row & 7) << 4);
            const u16* ga = A + (size_t)(m0 + row) * 512 + kt + (scol >> 1);
            __builtin_amdgcn_global_load_lds(
                (const __attribute__((address_space(1))) void*)ga,
                (__attribute__((address_space(3))) void*)(As + off), 16, 0, 0);
        }
#pragma unroll
        for (int i = 0; i < 4; ++i) {              // B: 128 rows x 128B
            int off = i * 4096 + tid * 16;
            int row = off >> 7, colb = off & 127;
            int scol = colb ^ ((row & 7) << 4);
            const u16* gb = B + (size_t)row * 512 + kt + (scol >> 1);
            __builtin_amdgcn_global_load_lds(
                (const __attribute__((address_space(1))) void*)gb,
                (__attribute__((address_space(3))) void*)(Bs + off), 16, 0, 0);
        }
    };

    stage(0, 0);
    stage(1, 64);
    asm volatile("s_waitcnt vmcnt(6)" ::: "memory");
    __builtin_amdgcn_sched_barrier(0);
    __builtin_amdgcn_s_barrier();
    __builtin_amdgcn_sched_barrier(0);

    int cur = 0;
    for (int t = 0; t < 8; ++t) {
        const char* As = lds + cur * 8192;
        const char* Bs = lds + 24576 + cur * 16384;
#pragma unroll
        for (int kk = 0; kk < 2; ++kk) {
            const int kb = (kk * 64 + (fq << 4)) ^ swz;
            f16x8 af[2], bfr[4];
#pragma unroll
            for (int mf = 0; mf < 2; ++mf)
                af[mf] = *(const f16x8*)(As + (wr * 32 + mf * 16 + fr) * 128 + kb);
#pragma unroll
            for (int nf = 0; nf < 4; ++nf)
                bfr[nf] = *(const f16x8*)(Bs + (wc * 64 + nf * 16 + fr) * 128 + kb);
#pragma unroll
            for (int mf = 0; mf < 2; ++mf)
#pragma unroll
                for (int nf = 0; nf < 4; ++nf)
                    acc[mf][nf] = __builtin_amdgcn_mfma_f32_16x16x32_f16(
                        af[mf], bfr[nf], acc[mf][nf], 0, 0, 0);
        }
        int nxt = cur + 2; if (nxt >= 3) nxt -= 3;
        if (t < 6) {
            stage(nxt, (t + 2) << 6);
            asm volatile("s_waitcnt vmcnt(6)" ::: "memory");
        } else {
            asm volatile("s_waitcnt vmcnt(0)" ::: "memory");
        }
        __builtin_amdgcn_sched_barrier(0);
        __builtin_amdgcn_s_barrier();
        __builtin_amdgcn_sched_barrier(0);
        cur += 1; if (cur >= 3) cur -= 3;
    }

#pragma unroll
    for (int mf = 0; mf < 2; ++mf) {
        int rbase = m0 + wr * 32 + mf * 16 + (fq << 2);
#pragma unroll
        for (int nf = 0; nf < 4; ++nf) {
            int o2 = wc * 64 + nf * 16 + fr;
            f32x4 v = acc[mf][nf];
#pragma unroll
            for (int r = 0; r < 4; ++r) {
                int colg = rbase + r;
                int b = (colg >= 8256) ? 1 : 0;
                int cell = colg - b * 8256;
                int dm = tab[cell];
                float z = fmaxf(v[r] + bias[o2], 0.f);
                out[((size_t)b << 21) + ((size_t)o2 << 14) + ((dm >> 8) << 7) + (dm & 255)] = z;
            }
        }
    }
}

// ws layout (bytes):
//   0         hT16   fp16 [2][128][128]           65536
//   65536     W3n    fp16 [32][512][128]          4194304
//   4259840   W2h    fp16 [128][512]              131072
//   4390912   c0     fp32 [128]                   512
//   4391424   tab    int  [8256] (alloc 16512)    66048
//   9741312   G      fp16 [2][512][4096]          8388608
//   18129920  m3T    fp16 [16512][512]            16908288
//   35038208  SMd    fp16 [8256][4096]            67633152
extern "C" void kernel_launch(void* const* d_in, const int* in_sizes, int n_in,
                              void* d_out, int out_size, void* d_ws, size_t ws_size,
                              hipStream_t stream) {
    const float* x     = (const float*)d_in[0];
    const float* w_red = (const float*)d_in[1];
    const float* b_red = (const float*)d_in[2];
    const float* w3d   = (const float*)d_in[3];
    const float* b3d   = (const float*)d_in[4];
    const float* w2d   = (const float*)d_in[5];
    const float* b2d   = (const float*)d_in[6];
    float* out = (float*)d_out;

    char* ws = (char*)d_ws;
    u16*   hT16  = (u16*)(ws + 0);
    u16*   W3n   = (u16*)(ws + 65536);
    u16*   W2h   = (u16*)(ws + 4259840);
    float* c0    = (float*)(ws + 4390912);
    int*   tab   = (int*)(ws + 4391424);
    u16*   G     = (u16*)(ws + 9741312);
    u16*   m3T   = (u16*)(ws + 18129920);
    u16*   SMd   = (u16*)(ws + 35038208);

    setup_kernel<<<2834, 256, 0, stream>>>(x, w_red, b_red, w3d, w2d, b3d, b2d,
                                           W3n, hT16, W2h, tab, c0, SMd);
    gkern<<<256, 256, 0, stream>>>(W3n, hT16, G);
    mega_kernel<<<520, 256, 0, stream>>>(G, SMd, b3d, m3T);
    gemm2f_kernel<<<514, 256, 0, stream>>>(m3T, W2h, b2d, tab, c0, out);
}

// Round 21
// 174.043 us; speedup vs baseline: 1.0823x; 1.0823x over previous
//
#include <hip/hip_runtime.h>

typedef unsigned short u16;
typedef unsigned int u32;
typedef unsigned long long u64;
typedef _Float16 f16x8 __attribute__((ext_vector_type(8)));
typedef float f32x4 __attribute__((ext_vector_type(4)));

__device__ __forceinline__ u16 f2h(float f) {
    _Float16 h = (_Float16)f;
    return __builtin_bit_cast(u16, h);
}

// ---- setup+smd (grid 2834): W3n | conv | W2h | tab | c0 | SMd (taps computed inline) ----
__global__ __launch_bounds__(256) void setup_kernel(
        const float* __restrict__ x, const float* __restrict__ w_red,
        const float* __restrict__ b_red, const float* __restrict__ w3d,
        const float* __restrict__ w2d, const float* __restrict__ b3,
        const float* __restrict__ b2,
        u16* __restrict__ W3n, u16* __restrict__ hT16,
        u16* __restrict__ W2h, int* __restrict__ tab,
        float* __restrict__ c0, u16* __restrict__ SMd) {
#pragma clang fp contract(off)
    __shared__ alignas(16) u16 rows[4][4096];
    int bid = blockIdx.x, tid = threadIdx.x;
    if (bid < 256) {                       // W3n[n][o*128+c] = fp16(w3d[o][c][n])
        int oc = bid * 256 + tid;
        float4 v[8];
        const float4* src = (const float4*)(w3d + (size_t)oc * 32);
#pragma unroll
        for (int j = 0; j < 8; ++j) v[j] = src[j];
        const float* vf = (const float*)v;
#pragma unroll
        for (int n = 0; n < 32; ++n)
            W3n[n * 65536 + oc] = f2h(vf[n]);
        return;
    }
    if (bid < 512) {                       // conv1d+ReLU -> hT16[b][t][c] fp16
        if (tid >= 128) return;
        int idx = bid - 256;
        int co = idx & 127, b = idx >> 7, t = tid;
        float acc = b_red[co];
        const float* xb = x + b * 256 * 128;
        const float* wr = w_red + co * 768;
        for (int ci = 0; ci < 256; ++ci) {
            float w0 = wr[ci * 3 + 0], w1 = wr[ci * 3 + 1], w2 = wr[ci * 3 + 2];
            float x1 = xb[ci * 128 + t];
            float x0 = (t >= 1)   ? xb[ci * 128 + t - 1] : 0.f;
            float x2 = (t < 127) ? xb[ci * 128 + t + 1] : 0.f;
            acc += x0 * w0 + x1 * w1 + x2 * w2;
        }
        hT16[b * 16384 + t * 128 + co] = f2h(fmaxf(acc, 0.f));
        return;
    }
    if (bid < 768) {                       // W2h
        int i = (bid - 512) * 256 + tid;
        W2h[i] = f2h(w2d[i]);
        return;
    }
    if (bid == 768) {                      // cell -> (d,m)
        for (int cell = tid; cell < 8256; cell += 256) {
            int off = 0, d = 0;
            while (d < 128) { int w = 128 - d; if (cell < off + w) break; off += w; ++d; }
            tab[cell] = (d << 8) | (cell - off);
        }
        return;
    }
    if (bid == 769) {                      // c0
        int o2 = tid >> 1, half = tid & 1;
        float s = 0.f;
        const float* row = w2d + o2 * 512 + half * 256;
        for (int o = 0; o < 256; ++o) s += row[o] * fmaxf(b3[half * 256 + o], 0.f);
        s += __shfl_xor(s, 1);
        if (half == 0) c0[o2] = fmaxf(s + b2[o2], 0.f);
        return;
    }
    // ---- SMd branch: 4 cells/block, taps computed inline (bit-exact math, verified) ----
    const int cid = tid >> 6, l = tid & 63;
    const int cell = (bid - 770) * 4 + cid;
    char* rowb = (char*)&rows[cid][0];
    f32x4 z = {0.f, 0.f, 0.f, 0.f};
#pragma unroll
    for (int j = 0; j < 8; ++j)
        *(f32x4*)(rowb + l * 128 + j * 16) = z;
    __syncthreads();
    if (l < 32) {
        int n = l;
        int off = 0, d = 0;
        while (d < 128) { int w = 128 - d; if (cell < off + w) break; off += w; ++d; }
        int m = cell - off;
        double xm = m - (d + 1) * 0.5;
        double step = (2 * d + 1) / 95.0;
        int t0 = (int)floor(xm + step * (double)(3 * n));
        int dnr[3], upr[3]; double av[3], bv[3];
#pragma unroll
        for (int j = 0; j < 3; ++j) {
            double p = step * (double)(3 * n + j);   // mul then add: matches numpy
            double s = xm + p;
            double tr = trunc(s);
            double dec = s - tr;
            int dn = (int)tr, up = (int)ceil(s);
            dnr[j] = dn - t0; upr[j] = up - t0;
            av[j] = (dn >= 0 && dn <= 127) ? (1.0 - dec) * (1.0 / 3.0) : 0.0;
            bv[j] = (up >= 0 && up <= 127) ? dec * (1.0 / 3.0) : 0.0;
        }
#pragma unroll
        for (int sl = 0; sl < 8; ++sl) {   // static composition (no scratch)
            double a = 0.0;
#pragma unroll
            for (int j = 0; j < 3; ++j) {
                a += (dnr[j] == sl) ? av[j] : 0.0;
                a += (upr[j] == sl) ? bv[j] : 0.0;
            }
            int t = t0 + sl;
            if ((unsigned)t < 128u)
                rows[cid][n * 128 + t] = f2h((float)a);
        }
    }
    __syncthreads();
    u16* dst = SMd + (size_t)cell * 4096;
#pragma unroll
    for (int j = 0; j < 8; ++j)
        *(f32x4*)((char*)dst + l * 16 + j * 1024) = *(const f32x4*)(rowb + l * 16 + j * 1024);
}

// ---------------- gkern: G[b][o][n*128+t] = sum_c W3n[n][o][c] * hT16[b][t][c] ----------
__global__ __launch_bounds__(256) void gkern(const u16* __restrict__ W3n,
                                             const u16* __restrict__ hT16,
                                             u16* __restrict__ G) {
    __shared__ alignas(16) u16 As[128 * 128];
    __shared__ alignas(16) u16 Bs[128 * 128];
    const int tid = threadIdx.x;
    const int lane = tid & 63, wv = tid >> 6;
    const int fr = lane & 15, fq = lane >> 4;
    const int bid = blockIdx.x;
    const int b = bid & 1, n = (bid >> 1) & 31, os = bid >> 6;
    const u16* Abase = W3n + n * 65536 + os * 128 * 128;
    const u16* Bbase = hT16 + b * 16384;
#pragma unroll
    for (int i = 0; i < 8; ++i) {
        int off = i * 4096 + tid * 16;
        int row = off >> 8, colb = off & 255;
        int scol = colb ^ ((row & 7) << 4);
        __builtin_amdgcn_global_load_lds(
            (const __attribute__((address_space(1))) void*)(Abase + row * 128 + (scol >> 1)),
            (__attribute__((address_space(3))) void*)((char*)As + off), 16, 0, 0);
        __builtin_amdgcn_global_load_lds(
            (const __attribute__((address_space(1))) void*)(Bbase + row * 128 + (scol >> 1)),
            (__attribute__((address_space(3))) void*)((char*)Bs + off), 16, 0, 0);
    }
    asm volatile("s_waitcnt vmcnt(0)" ::: "memory");
    __syncthreads();
    const int wm = wv >> 1, wn = wv & 1;
    f32x4 acc[4][4] = {};
#pragma unroll
    for (int kk = 0; kk < 4; ++kk) {
        int kb = kk * 64 + fq * 16;
        f16x8 af[4], bf[4];
#pragma unroll
        for (int mf = 0; mf < 4; ++mf) {
            int row = wm * 64 + mf * 16 + fr;
            af[mf] = *(const f16x8*)((const char*)As + row * 256 + (kb ^ ((row & 7) << 4)));
        }
#pragma unroll
        for (int nf = 0; nf < 4; ++nf) {
            int row = wn * 64 + nf * 16 + fr;
            bf[nf] = *(const f16x8*)((const char*)Bs + row * 256 + (kb ^ ((row & 7) << 4)));
        }
#pragma unroll
        for (int mf = 0; mf < 4; ++mf)
#pragma unroll
            for (int nf = 0; nf < 4; ++nf)
                acc[mf][nf] = __builtin_amdgcn_mfma_f32_16x16x32_f16(
                    af[mf], bf[nf], acc[mf][nf], 0, 0, 0);
    }
    u16* Gb = G + (size_t)b * 2097152;
#pragma unroll
    for (int mf = 0; mf < 4; ++mf) {
        int o = os * 128 + wm * 64 + mf * 16 + (fq << 2);
#pragma unroll
        for (int nf = 0; nf < 4; ++nf) {
            int t = wn * 64 + nf * 16 + fr;
            f32x4 v = acc[mf][nf];
#pragma unroll
            for (int r = 0; r < 4; ++r)
                Gb[(size_t)(o + r) * 4096 + n * 128 + t] = f2h(v[r]);
        }
    }
}

// ---------------- GEMM1 v13 (R19-proven) + fill blocks 520..775 ------------------------
// A = G[1024][4096], B = SMd[8256][4096]. BM=128, BN=128, BK=64. 256 thr, 4 waves (2x2),
// wave tile 64x64. LDS 80KB = A 3x16KB @0 + B 2x16KB @49152 -> 2 blocks/CU. ONE barrier:
// iter t: stageB(t+1 -> (t+1)&1) | compute(A[t%3],B[t&1]) | stageA(t+2 -> (t+2)%3) |
// vmcnt(4) | s_barrier. Grid 520 GEMM + 256 fill (pure writes, overlap mega's compute).
__global__ __launch_bounds__(256, 2) void mega_kernel(
        const u16* __restrict__ G, const u16* __restrict__ SMd,
        const float* __restrict__ b3, u16* __restrict__ m3T,
        const float* __restrict__ c0, float* __restrict__ out) {
    __shared__ alignas(16) char lds[81920];

    if (blockIdx.x >= 520) {                       // fill part (no LDS/barrier use)
        int idx = blockIdx.x - 520;                // [0,256)
        int d = idx & 127, b = idx >> 7;
        if (d == 0) return;
        int cnt = d, total = 128 * cnt;
        for (int j = threadIdx.x; j < total; j += blockDim.x) {
            int o2 = j / cnt, m = 128 - cnt + (j % cnt);
            out[((size_t)b << 21) + ((size_t)o2 << 14) + (d << 7) + m] = c0[o2];
        }
        return;
    }

    const int tid = threadIdx.x;
    const int lane = tid & 63, wv = tid >> 6;
    const int fr = lane & 15, fq = lane >> 4;
    const int swz = (fr & 7) << 4;
    const int wm = wv >> 1, wn = wv & 1;           // 2m x 2n wave grid

    const int id = blockIdx.x;
    int p, s;
    if (id < 512) { int c = id >> 6, r = id & 63; p = c * 8 + (r & 7); s = r >> 3; }
    else          { p = 64; s = id - 512; }
    const int cell0 = p * 128;
    const int cn = (p == 64) ? 64 : 128;
    const int m0 = s * 128;

    f32x4 acc[4][4] = {};

    auto stageA = [&](int buf, int kt) {           // 4 global_load_lds
        char* A = lds + buf * 16384;
#pragma unroll
        for (int i2 = 0; i2 < 4; ++i2) {
            int off = i2 * 4096 + tid * 16;
            int row = off >> 7, colb = off & 127;
            int scol = colb ^ ((row & 7) << 4);
            const u16* ga = G + (size_t)(m0 + row) * 4096 + kt + (scol >> 1);
            __builtin_amdgcn_global_load_lds(
                (const __attribute__((address_space(1))) void*)ga,
                (__attribute__((address_space(3))) void*)(A + off), 16, 0, 0);
        }
    };
    auto stageB = [&](int buf, int kt) {           // 4 global_load_lds
        char* B = lds + 49152 + buf * 16384;
#pragma unroll
        for (int i2 = 0; i2 < 4; ++i2) {
            int off = i2 * 4096 + tid * 16;
            int row = off >> 7, colb = off & 127;
            int r2 = row < cn ? row : 0;
            int scol = colb ^ ((row & 7) << 4);
            const u16* gb = SMd + (size_t)(cell0 + r2) * 4096 + kt + (scol >> 1);
            __builtin_amdgcn_global_load_lds(
                (const __attribute__((address_space(1))) void*)gb,
                (__attribute__((address_space(3))) void*)(B + off), 16, 0, 0);
        }
    };

    // prologue: B(0), A(0) needed first; A(1) may stay in flight
    stageB(0, 0);
    stageA(0, 0);
    stageA(1, 64);
    asm volatile("s_waitcnt vmcnt(4)" ::: "memory");   // B(0)+A(0) done
    __builtin_amdgcn_sched_barrier(0);
    __builtin_amdgcn_s_barrier();
    __builtin_amdgcn_sched_barrier(0);

    int cur = 0;                                   // t % 3
    for (int t = 0; t < 64; ++t) {
        if (t < 63) stageB((t + 1) & 1, (t + 1) << 6);
        const char* A = lds + cur * 16384;
        const char* Bp = lds + 49152 + (t & 1) * 16384;
#pragma unroll
        for (int kk = 0; kk < 2; ++kk) {
            const int kb = (kk * 64 + (fq << 4)) ^ swz;
            f16x8 af[4], bfr[4];
#pragma unroll
            for (int mf = 0; mf < 4; ++mf)
                af[mf] = *(const f16x8*)(A + (wm * 64 + mf * 16 + fr) * 128 + kb);
#pragma unroll
            for (int nf = 0; nf < 4; ++nf)
                bfr[nf] = *(const f16x8*)(Bp + (wn * 64 + nf * 16 + fr) * 128 + kb);
            __builtin_amdgcn_s_setprio(1);
#pragma unroll
            for (int mf = 0; mf < 4; ++mf)
#pragma unroll
                for (int nf = 0; nf < 4; ++nf)
                    acc[mf][nf] = __builtin_amdgcn_mfma_f32_16x16x32_f16(
                        af[mf], bfr[nf], acc[mf][nf], 0, 0, 0);
            __builtin_amdgcn_s_setprio(0);
        }
        int nxt = cur + 2; if (nxt >= 3) nxt -= 3;            // (t+2) % 3
        if (t < 62) {
            stageA(nxt, (t + 2) << 6);
            asm volatile("s_waitcnt vmcnt(4)" ::: "memory");  // A(t+1),B(t+1) landed
        } else {
            asm volatile("s_waitcnt vmcnt(0)" ::: "memory");
        }
        __builtin_amdgcn_sched_barrier(0);
        __builtin_amdgcn_s_barrier();              // the ONLY barrier per iteration
        __builtin_amdgcn_sched_barrier(0);
        cur += 1; if (cur >= 3) cur -= 3;
    }

    // epilogue: m = m0 + wm*64 + mf*16 + fq*4 + r -> (b = m>>9, o = m&511)
#pragma unroll
    for (int mf = 0; mf < 4; ++mf) {
        int m = m0 + wm * 64 + mf * 16 + (fq << 2);
        int b = m >> 9, o = m & 511;
#pragma unroll
        for (int nf = 0; nf < 4; ++nf) {
            int cl = wn * 64 + nf * 16 + fr;
            if (cl < cn) {
                f32x4 v = acc[mf][nf];
                u64 pw = 0;
#pragma unroll
                for (int r = 0; r < 4; ++r) {
                    float z = fmaxf(v[r] + b3[o + r], 0.f);
                    pw |= (u64)f2h(z) << (16 * r);
                }
                *(u64*)(m3T + ((size_t)(b * 8256 + cell0 + cl)) * 512 + o) = pw;
            }
        }
    }
}

// ---------------- GEMM2: pure one-barrier tribuf GEMM (fill moved to mega) -------------
__global__ __launch_bounds__(256, 2) void gemm2f_kernel(const u16* __restrict__ A,
                                                        const u16* __restrict__ B,
                                                        const float* __restrict__ bias,
                                                        const int* __restrict__ tab,
                                                        float* __restrict__ out) {
    __shared__ alignas(16) char lds[73728];        // As 3x8KB @0, Bs 3x16KB @24576
    const int tid = threadIdx.x;
    const int lane = tid & 63, wave = tid >> 6;
    const int m0 = blockIdx.x * 64;
    const int wr = wave & 1, wc = wave >> 1;
    const int fr = lane & 15, fq = lane >> 4;
    const int swz = (fr & 7) << 4;
    f32x4 acc[2][4] = {};

    auto stage = [&](int buf, int kt) {            // 6 loads per thread
        char* As = lds + buf * 8192;
        char* Bs = lds + 24576 + buf * 16384;
#pragma unroll
        for (int i = 0; i < 2; ++i) {              // A: 64 rows x 128B
            int off = i * 4096 + tid * 16;
            int row = off >> 7, colb = off & 127;
            int scol = colb ^ ((row & 7) << 4);
            const u16* ga = A + (size_t)(m0 + row) * 512 + kt + (scol >> 1);
            __builtin_amdgcn_global_load_lds(
                (const __attribute__((address_space(1))) void*)ga,
                (__attribute__((address_space(3))) void*)(As + off), 16, 0, 0);
        }
#pragma unroll
        for (int i = 0; i < 4; ++i) {              // B: 128 rows x 128B
            int off = i * 4096 + tid * 16;
            int row = off >> 7, colb = off & 127;
            int scol = colb ^ ((row & 7) << 4);
            const u16* gb = B + (size_t)row * 512 + kt + (scol >> 1);
            __builtin_amdgcn_global_load_lds(
                (const __attribute__((address_space(1))) void*)gb,
                (__attribute__((address_space(3))) void*)(Bs + off), 16, 0, 0);
        }
    };

    stage(0, 0);
    stage(1, 64);
    asm volatile("s_waitcnt vmcnt(6)" ::: "memory");
    __builtin_amdgcn_sched_barrier(0);
    __builtin_amdgcn_s_barrier();
    __builtin_amdgcn_sched_barrier(0);

    int cur = 0;
    for (int t = 0; t < 8; ++t) {
        const char* As = lds + cur * 8192;
        const char* Bs = lds + 24576 + cur * 16384;
#pragma unroll
        for (int kk = 0; kk < 2; ++kk) {
            const int kb = (kk * 64 + (fq << 4)) ^ swz;
            f16x8 af[2], bfr[4];
#pragma unroll
            for (int mf = 0; mf < 2; ++mf)
                af[mf] = *(const f16x8*)(As + (wr * 32 + mf * 16 + fr) * 128 + kb);
#pragma unroll
            for (int nf = 0; nf < 4; ++nf)
                bfr[nf] = *(const f16x8*)(Bs + (wc * 64 + nf * 16 + fr) * 128 + kb);
#pragma unroll
            for (int mf = 0; mf < 2; ++mf)
#pragma unroll
                for (int nf = 0; nf < 4; ++nf)
                    acc[mf][nf] = __builtin_amdgcn_mfma_f32_16x16x32_f16(
                        af[mf], bfr[nf], acc[mf][nf], 0, 0, 0);
        }
        int nxt = cur + 2; if (nxt >= 3) nxt -= 3;
        if (t < 6) {
            stage(nxt, (t + 2) << 6);
            asm volatile("s_waitcnt vmcnt(6)" ::: "memory");
        } else {
            asm volatile("s_waitcnt vmcnt(0)" ::: "memory");
        }
        __builtin_amdgcn_sched_barrier(0);
        __builtin_amdgcn_s_barrier();
        __builtin_amdgcn_sched_barrier(0);
        cur += 1; if (cur >= 3) cur -= 3;
    }

#pragma unroll
    for (int mf = 0; mf < 2; ++mf) {
        int rbase = m0 + wr * 32 + mf * 16 + (fq << 2);
#pragma unroll
        for (int nf = 0; nf < 4; ++nf) {
            int o2 = wc * 64 + nf * 16 + fr;
            f32x4 v = acc[mf][nf];
#pragma unroll
            for (int r = 0; r < 4; ++r) {
                int colg = rbase + r;
                int b = (colg >= 8256) ? 1 : 0;
                int cell = colg - b * 8256;
                int dm = tab[cell];
                float z = fmaxf(v[r] + bias[o2], 0.f);
                out[((size_t)b << 21) + ((size_t)o2 << 14) + ((dm >> 8) << 7) + (dm & 255)] = z;
            }
        }
    }
}

// ws layout (bytes):
//   0         hT16   fp16 [2][128][128]           65536
//   65536     W3n    fp16 [32][512][128]          4194304
//   4259840   W2h    fp16 [128][512]              131072
//   4390912   c0     fp32 [128]                   512
//   4391424   tab    int  [8256] (alloc 16512)    66048
//   9741312   G      fp16 [2][512][4096]          8388608
//   18129920  m3T    fp16 [16512][512]            16908288
//   35038208  SMd    fp16 [8256][4096]            67633152
extern "C" void kernel_launch(void* const* d_in, const int* in_sizes, int n_in,
                              void* d_out, int out_size, void* d_ws, size_t ws_size,
                              hipStream_t stream) {
    const float* x     = (const float*)d_in[0];
    const float* w_red = (const float*)d_in[1];
    const float* b_red = (const float*)d_in[2];
    const float* w3d   = (const float*)d_in[3];
    const float* b3d   = (const float*)d_in[4];
    const float* w2d   = (const float*)d_in[5];
    const float* b2d   = (const float*)d_in[6];
    float* out = (float*)d_out;

    char* ws = (char*)d_ws;
    u16*   hT16  = (u16*)(ws + 0);
    u16*   W3n   = (u16*)(ws + 65536);
    u16*   W2h   = (u16*)(ws + 4259840);
    float* c0    = (float*)(ws + 4390912);
    int*   tab   = (int*)(ws + 4391424);
    u16*   G     = (u16*)(ws + 9741312);
    u16*   m3T   = (u16*)(ws + 18129920);
    u16*   SMd   = (u16*)(ws + 35038208);

    setup_kernel<<<2834, 256, 0, stream>>>(x, w_red, b_red, w3d, w2d, b3d, b2d,
                                           W3n, hT16, W2h, tab, c0, SMd);
    gkern<<<256, 256, 0, stream>>>(W3n, hT16, G);
    mega_kernel<<<776, 256, 0, stream>>>(G, SMd, b3d, m3T, c0, out);
    gemm2f_kernel<<<258, 256, 0, stream>>>(m3T, W2h, b2d, tab, out);
}

// Round 22
// 173.811 us; speedup vs baseline: 1.0837x; 1.0013x over previous
//
#include <hip/hip_runtime.h>

typedef unsigned short u16;
typedef unsigned int u32;
typedef unsigned long long u64;
typedef _Float16 f16x8 __attribute__((ext_vector_type(8)));
typedef float f32x4 __attribute__((ext_vector_type(4)));

__device__ __forceinline__ u16 f2h(float f) {
    _Float16 h = (_Float16)f;
    return __builtin_bit_cast(u16, h);
}

// ---- setup+smd (grid 2834): W3n | conv | W2h | tab | c0 | SMd (taps computed inline) ----
__global__ __launch_bounds__(256) void setup_kernel(
        const float* __restrict__ x, const float* __restrict__ w_red,
        const float* __restrict__ b_red, const float* __restrict__ w3d,
        const float* __restrict__ w2d, const float* __restrict__ b3,
        const float* __restrict__ b2,
        u16* __restrict__ W3n, u16* __restrict__ hT16,
        u16* __restrict__ W2h, int* __restrict__ tab,
        float* __restrict__ c0, u16* __restrict__ SMd) {
#pragma clang fp contract(off)
    __shared__ alignas(16) u16 rows[4][4096];
    int bid = blockIdx.x, tid = threadIdx.x;
    if (bid < 256) {                       // W3n[n][o*128+c] = fp16(w3d[o][c][n])
        int oc = bid * 256 + tid;
        float4 v[8];
        const float4* src = (const float4*)(w3d + (size_t)oc * 32);
#pragma unroll
        for (int j = 0; j < 8; ++j) v[j] = src[j];
        const float* vf = (const float*)v;
#pragma unroll
        for (int n = 0; n < 32; ++n)
            W3n[n * 65536 + oc] = f2h(vf[n]);
        return;
    }
    if (bid < 512) {                       // conv1d+ReLU -> hT16[b][t][c] fp16
        if (tid >= 128) return;
        int idx = bid - 256;
        int co = idx & 127, b = idx >> 7, t = tid;
        float acc = b_red[co];
        const float* xb = x + b * 256 * 128;
        const float* wr = w_red + co * 768;
        for (int ci = 0; ci < 256; ++ci) {
            float w0 = wr[ci * 3 + 0], w1 = wr[ci * 3 + 1], w2 = wr[ci * 3 + 2];
            float x1 = xb[ci * 128 + t];
            float x0 = (t >= 1)   ? xb[ci * 128 + t - 1] : 0.f;
            float x2 = (t < 127) ? xb[ci * 128 + t + 1] : 0.f;
            acc += x0 * w0 + x1 * w1 + x2 * w2;
        }
        hT16[b * 16384 + t * 128 + co] = f2h(fmaxf(acc, 0.f));
        return;
    }
    if (bid < 768) {                       // W2h
        int i = (bid - 512) * 256 + tid;
        W2h[i] = f2h(w2d[i]);
        return;
    }
    if (bid == 768) {                      // cell -> (d,m)
        for (int cell = tid; cell < 8256; cell += 256) {
            int off = 0, d = 0;
            while (d < 128) { int w = 128 - d; if (cell < off + w) break; off += w; ++d; }
            tab[cell] = (d << 8) | (cell - off);
        }
        return;
    }
    if (bid == 769) {                      // c0
        int o2 = tid >> 1, half = tid & 1;
        float s = 0.f;
        const float* row = w2d + o2 * 512 + half * 256;
        for (int o = 0; o < 256; ++o) s += row[o] * fmaxf(b3[half * 256 + o], 0.f);
        s += __shfl_xor(s, 1);
        if (half == 0) c0[o2] = fmaxf(s + b2[o2], 0.f);
        return;
    }
    // ---- SMd branch: 4 cells/block, taps computed inline (bit-exact math, verified) ----
    const int cid = tid >> 6, l = tid & 63;
    const int cell = (bid - 770) * 4 + cid;
    char* rowb = (char*)&rows[cid][0];
    f32x4 z = {0.f, 0.f, 0.f, 0.f};
#pragma unroll
    for (int j = 0; j < 8; ++j)
        *(f32x4*)(rowb + l * 128 + j * 16) = z;
    __syncthreads();
    if (l < 32) {
        int n = l;
        int off = 0, d = 0;
        while (d < 128) { int w = 128 - d; if (cell < off + w) break; off += w; ++d; }
        int m = cell - off;
        double xm = m - (d + 1) * 0.5;
        double step = (2 * d + 1) / 95.0;
        int t0 = (int)floor(xm + step * (double)(3 * n));
        int dnr[3], upr[3]; double av[3], bv[3];
#pragma unroll
        for (int j = 0; j < 3; ++j) {
            double p = step * (double)(3 * n + j);   // mul then add: matches numpy
            double s = xm + p;
            double tr = trunc(s);
            double dec = s - tr;
            int dn = (int)tr, up = (int)ceil(s);
            dnr[j] = dn - t0; upr[j] = up - t0;
            av[j] = (dn >= 0 && dn <= 127) ? (1.0 - dec) * (1.0 / 3.0) : 0.0;
            bv[j] = (up >= 0 && up <= 127) ? dec * (1.0 / 3.0) : 0.0;
        }
#pragma unroll
        for (int sl = 0; sl < 8; ++sl) {   // static composition (no scratch)
            double a = 0.0;
#pragma unroll
            for (int j = 0; j < 3; ++j) {
                a += (dnr[j] == sl) ? av[j] : 0.0;
                a += (upr[j] == sl) ? bv[j] : 0.0;
            }
            int t = t0 + sl;
            if ((unsigned)t < 128u)
                rows[cid][n * 128 + t] = f2h((float)a);
        }
    }
    __syncthreads();
    u16* dst = SMd + (size_t)cell * 4096;
#pragma unroll
    for (int j = 0; j < 8; ++j)
        *(f32x4*)((char*)dst + l * 16 + j * 1024) = *(const f32x4*)(rowb + l * 16 + j * 1024);
}

// ---------------- gkern: G[b][o][n*128+t] = sum_c W3n[n][o][c] * hT16[b][t][c] ----------
__global__ __launch_bounds__(256) void gkern(const u16* __restrict__ W3n,
                                             const u16* __restrict__ hT16,
                                             u16* __restrict__ G) {
    __shared__ alignas(16) u16 As[128 * 128];
    __shared__ alignas(16) u16 Bs[128 * 128];
    const int tid = threadIdx.x;
    const int lane = tid & 63, wv = tid >> 6;
    const int fr = lane & 15, fq = lane >> 4;
    const int bid = blockIdx.x;
    const int b = bid & 1, n = (bid >> 1) & 31, os = bid >> 6;
    const u16* Abase = W3n + n * 65536 + os * 128 * 128;
    const u16* Bbase = hT16 + b * 16384;
#pragma unroll
    for (int i = 0; i < 8; ++i) {
        int off = i * 4096 + tid * 16;
        int row = off >> 8, colb = off & 255;
        int scol = colb ^ ((row & 7) << 4);
        __builtin_amdgcn_global_load_lds(
            (const __attribute__((address_space(1))) void*)(Abase + row * 128 + (scol >> 1)),
            (__attribute__((address_space(3))) void*)((char*)As + off), 16, 0, 0);
        __builtin_amdgcn_global_load_lds(
            (const __attribute__((address_space(1))) void*)(Bbase + row * 128 + (scol >> 1)),
            (__attribute__((address_space(3))) void*)((char*)Bs + off), 16, 0, 0);
    }
    asm volatile("s_waitcnt vmcnt(0)" ::: "memory");
    __syncthreads();
    const int wm = wv >> 1, wn = wv & 1;
    f32x4 acc[4][4] = {};
#pragma unroll
    for (int kk = 0; kk < 4; ++kk) {
        int kb = kk * 64 + fq * 16;
        f16x8 af[4], bf[4];
#pragma unroll
        for (int mf = 0; mf < 4; ++mf) {
            int row = wm * 64 + mf * 16 + fr;
            af[mf] = *(const f16x8*)((const char*)As + row * 256 + (kb ^ ((row & 7) << 4)));
        }
#pragma unroll
        for (int nf = 0; nf < 4; ++nf) {
            int row = wn * 64 + nf * 16 + fr;
            bf[nf] = *(const f16x8*)((const char*)Bs + row * 256 + (kb ^ ((row & 7) << 4)));
        }
#pragma unroll
        for (int mf = 0; mf < 4; ++mf)
#pragma unroll
            for (int nf = 0; nf < 4; ++nf)
                acc[mf][nf] = __builtin_amdgcn_mfma_f32_16x16x32_f16(
                    af[mf], bf[nf], acc[mf][nf], 0, 0, 0);
    }
    u16* Gb = G + (size_t)b * 2097152;
#pragma unroll
    for (int mf = 0; mf < 4; ++mf) {
        int o = os * 128 + wm * 64 + mf * 16 + (fq << 2);
#pragma unroll
        for (int nf = 0; nf < 4; ++nf) {
            int t = wn * 64 + nf * 16 + fr;
            f32x4 v = acc[mf][nf];
#pragma unroll
            for (int r = 0; r < 4; ++r)
                Gb[(size_t)(o + r) * 4096 + n * 128 + t] = f2h(v[r]);
        }
    }
}

// ---------------- GEMM1 v13b: R21 structure, setprio REMOVED (m190: hurts non-8-phase) --
// A = G[1024][4096], B = SMd[8256][4096]. BM=128, BN=128, BK=64. 256 thr, 4 waves (2x2),
// wave tile 64x64. LDS 80KB = A 3x16KB @0 + B 2x16KB @49152 -> 2 blocks/CU. ONE barrier:
// iter t: stageB(t+1 -> (t+1)&1) | compute(A[t%3],B[t&1]) | stageA(t+2 -> (t+2)%3) |
// vmcnt(4) | s_barrier. Grid 520 GEMM + 256 fill (pure writes, overlap mega's compute).
__global__ __launch_bounds__(256, 2) void mega_kernel(
        const u16* __restrict__ G, const u16* __restrict__ SMd,
        const float* __restrict__ b3, u16* __restrict__ m3T,
        const float* __restrict__ c0, float* __restrict__ out) {
    __shared__ alignas(16) char lds[81920];

    if (blockIdx.x >= 520) {                       // fill part (no LDS/barrier use)
        int idx = blockIdx.x - 520;                // [0,256)
        int d = idx & 127, b = idx >> 7;
        if (d == 0) return;
        int cnt = d, total = 128 * cnt;
        for (int j = threadIdx.x; j < total; j += blockDim.x) {
            int o2 = j / cnt, m = 128 - cnt + (j % cnt);
            out[((size_t)b << 21) + ((size_t)o2 << 14) + (d << 7) + m] = c0[o2];
        }
        return;
    }

    const int tid = threadIdx.x;
    const int lane = tid & 63, wv = tid >> 6;
    const int fr = lane & 15, fq = lane >> 4;
    const int swz = (fr & 7) << 4;
    const int wm = wv >> 1, wn = wv & 1;           // 2m x 2n wave grid

    const int id = blockIdx.x;
    int p, s;
    if (id < 512) { int c = id >> 6, r = id & 63; p = c * 8 + (r & 7); s = r >> 3; }
    else          { p = 64; s = id - 512; }
    const int cell0 = p * 128;
    const int cn = (p == 64) ? 64 : 128;
    const int m0 = s * 128;

    f32x4 acc[4][4] = {};

    auto stageA = [&](int buf, int kt) {           // 4 global_load_lds
        char* A = lds + buf * 16384;
#pragma unroll
        for (int i2 = 0; i2 < 4; ++i2) {
            int off = i2 * 4096 + tid * 16;
            int row = off >> 7, colb = off & 127;
            int scol = colb ^ ((row & 7) << 4);
            const u16* ga = G + (size_t)(m0 + row) * 4096 + kt + (scol >> 1);
            __builtin_amdgcn_global_load_lds(
                (const __attribute__((address_space(1))) void*)ga,
                (__attribute__((address_space(3))) void*)(A + off), 16, 0, 0);
        }
    };
    auto stageB = [&](int buf, int kt) {           // 4 global_load_lds
        char* B = lds + 49152 + buf * 16384;
#pragma unroll
        for (int i2 = 0; i2 < 4; ++i2) {
            int off = i2 * 4096 + tid * 16;
            int row = off >> 7, colb = off & 127;
            int r2 = row < cn ? row : 0;
            int scol = colb ^ ((row & 7) << 4);
            const u16* gb = SMd + (size_t)(cell0 + r2) * 4096 + kt + (scol >> 1);
            __builtin_amdgcn_global_load_lds(
                (const __attribute__((address_space(1))) void*)gb,
                (__attribute__((address_space(3))) void*)(B + off), 16, 0, 0);
        }
    };

    // prologue: B(0), A(0) needed first; A(1) may stay in flight
    stageB(0, 0);
    stageA(0, 0);
    stageA(1, 64);
    asm volatile("s_waitcnt vmcnt(4)" ::: "memory");   // B(0)+A(0) done
    __builtin_amdgcn_sched_barrier(0);
    __builtin_amdgcn_s_barrier();
    __builtin_amdgcn_sched_barrier(0);

    int cur = 0;                                   // t % 3
    for (int t = 0; t < 64; ++t) {
        if (t < 63) stageB((t + 1) & 1, (t + 1) << 6);
        const char* A = lds + cur * 16384;
        const char* Bp = lds + 49152 + (t & 1) * 16384;
#pragma unroll
        for (int kk = 0; kk < 2; ++kk) {
            const int kb = (kk * 64 + (fq << 4)) ^ swz;
            f16x8 af[4], bfr[4];
#pragma unroll
            for (int mf = 0; mf < 4; ++mf)
                af[mf] = *(const f16x8*)(A + (wm * 64 + mf * 16 + fr) * 128 + kb);
#pragma unroll
            for (int nf = 0; nf < 4; ++nf)
                bfr[nf] = *(const f16x8*)(Bp + (wn * 64 + nf * 16 + fr) * 128 + kb);
#pragma unroll
            for (int mf = 0; mf < 4; ++mf)
#pragma unroll
                for (int nf = 0; nf < 4; ++nf)
                    acc[mf][nf] = __builtin_amdgcn_mfma_f32_16x16x32_f16(
                        af[mf], bfr[nf], acc[mf][nf], 0, 0, 0);
        }
        int nxt = cur + 2; if (nxt >= 3) nxt -= 3;            // (t+2) % 3
        if (t < 62) {
            stageA(nxt, (t + 2) << 6);
            asm volatile("s_waitcnt vmcnt(4)" ::: "memory");  // A(t+1),B(t+1) landed
        } else {
            asm volatile("s_waitcnt vmcnt(0)" ::: "memory");
        }
        __builtin_amdgcn_sched_barrier(0);
        __builtin_amdgcn_s_barrier();              // the ONLY barrier per iteration
        __builtin_amdgcn_sched_barrier(0);
        cur += 1; if (cur >= 3) cur -= 3;
    }

    // epilogue: m = m0 + wm*64 + mf*16 + fq*4 + r -> (b = m>>9, o = m&511)
#pragma unroll
    for (int mf = 0; mf < 4; ++mf) {
        int m = m0 + wm * 64 + mf * 16 + (fq << 2);
        int b = m >> 9, o = m & 511;
#pragma unroll
        for (int nf = 0; nf < 4; ++nf) {
            int cl = wn * 64 + nf * 16 + fr;
            if (cl < cn) {
                f32x4 v = acc[mf][nf];
                u64 pw = 0;
#pragma unroll
                for (int r = 0; r < 4; ++r) {
                    float z = fmaxf(v[r] + b3[o + r], 0.f);
                    pw |= (u64)f2h(z) << (16 * r);
                }
                *(u64*)(m3T + ((size_t)(b * 8256 + cell0 + cl)) * 512 + o) = pw;
            }
        }
    }
}

// ---------------- GEMM2: pure one-barrier tribuf GEMM (fill lives in mega) -------------
__global__ __launch_bounds__(256, 2) void gemm2f_kernel(const u16* __restrict__ A,
                                                        const u16* __restrict__ B,
                                                        const float* __restrict__ bias,
                                                        const int* __restrict__ tab,
                                                        float* __restrict__ out) {
    __shared__ alignas(16) char lds[73728];        // As 3x8KB @0, Bs 3x16KB @24576
    const int tid = threadIdx.x;
    const int lane = tid & 63, wave = tid >> 6;
    const int m0 = blockIdx.x * 64;
    const int wr = wave & 1, wc = wave >> 1;
    const int fr = lane & 15, fq = lane >> 4;
    const int swz = (fr & 7) << 4;
    f32x4 acc[2][4] = {};

    auto stage = [&](int buf, int kt) {            // 6 loads per thread
        char* As = lds + buf * 8192;
        char* Bs = lds + 24576 + buf * 16384;
#pragma unroll
        for (int i = 0; i < 2; ++i) {              // A: 64 rows x 128B
            int off = i * 4096 + tid * 16;
            int row = off >> 7, colb = off & 127;
            int scol = colb ^ ((row & 7) << 4);
            const u16* ga = A + (size_t)(m0 + row) * 512 + kt + (scol >> 1);
            __builtin_amdgcn_global_load_lds(
                (const __attribute__((address_space(1))) void*)ga,
                (__attribute__((address_space(3))) void*)(As + off), 16, 0, 0);
        }
#pragma unroll
        for (int i = 0; i < 4; ++i) {              // B: 128 rows x 128B
            int off = i * 4096 + tid * 16;
            int row = off >> 7, colb = off & 127;
            int scol = colb ^ ((row & 7) << 4);
            const u16* gb = B + (size_t)row * 512 + kt + (scol >> 1);
            __builtin_amdgcn_global_load_lds(
                (const __attribute__((address_space(1))) void*)gb,
                (__attribute__((address_space(3))) void*)(Bs + off), 16, 0, 0);
        }
    };

    stage(0, 0);
    stage(1, 64);
    asm volatile("s_waitcnt vmcnt(6)" ::: "memory");
    __builtin_amdgcn_sched_barrier(0);
    __builtin_amdgcn_s_barrier();
    __builtin_amdgcn_sched_barrier(0);

    int cur = 0;
    for (int t = 0; t < 8; ++t) {
        const char* As = lds + cur * 8192;
        const char* Bs = lds + 24576 + cur * 16384;
#pragma unroll
        for (int kk = 0; kk < 2; ++kk) {
            const int kb = (kk * 64 + (fq << 4)) ^ swz;
            f16x8 af[2], bfr[4];
#pragma unroll
            for (int mf = 0; mf < 2; ++mf)
                af[mf] = *(const f16x8*)(As + (wr * 32 + mf * 16 + fr) * 128 + kb);
#pragma unroll
            for (int nf = 0; nf < 4; ++nf)
                bfr[nf] = *(const f16x8*)(Bs + (wc * 64 + nf * 16 + fr) * 128 + kb);
#pragma unroll
            for (int mf = 0; mf < 2; ++mf)
#pragma unroll
                for (int nf = 0; nf < 4; ++nf)
                    acc[mf][nf] = __builtin_amdgcn_mfma_f32_16x16x32_f16(
                        af[mf], bfr[nf], acc[mf][nf], 0, 0, 0);
        }
        int nxt = cur + 2; if (nxt >= 3) nxt -= 3;
        if (t < 6) {
            stage(nxt, (t + 2) << 6);
            asm volatile("s_waitcnt vmcnt(6)" ::: "memory");
        } else {
            asm volatile("s_waitcnt vmcnt(0)" ::: "memory");
        }
        __builtin_amdgcn_sched_barrier(0);
        __builtin_amdgcn_s_barrier();
        __builtin_amdgcn_sched_barrier(0);
        cur += 1; if (cur >= 3) cur -= 3;
    }

#pragma unroll
    for (int mf = 0; mf < 2; ++mf) {
        int rbase = m0 + wr * 32 + mf * 16 + (fq << 2);
#pragma unroll
        for (int nf = 0; nf < 4; ++nf) {
            int o2 = wc * 64 + nf * 16 + fr;
            f32x4 v = acc[mf][nf];
#pragma unroll
            for (int r = 0; r < 4; ++r) {
                int colg = rbase + r;
                int b = (colg >= 8256) ? 1 : 0;
                int cell = colg - b * 8256;
                int dm = tab[cell];
                float z = fmaxf(v[r] + bias[o2], 0.f);
                out[((size_t)b << 21) + ((size_t)o2 << 14) + ((dm >> 8) << 7) + (dm & 255)] = z;
            }
        }
    }
}

// ws layout (bytes):
//   0         hT16   fp16 [2][128][128]           65536
//   65536     W3n    fp16 [32][512][128]          4194304
//   4259840   W2h    fp16 [128][512]              131072
//   4390912   c0     fp32 [128]                   512
//   4391424   tab    int  [8256] (alloc 16512)    66048
//   9741312   G      fp16 [2][512][4096]          8388608
//   18129920  m3T    fp16 [16512][512]            16908288
//   35038208  SMd    fp16 [8256][4096]            67633152
extern "C" void kernel_launch(void* const* d_in, const int* in_sizes, int n_in,
                              void* d_out, int out_size, void* d_ws, size_t ws_size,
                              hipStream_t stream) {
    const float* x     = (const float*)d_in[0];
    const float* w_red = (const float*)d_in[1];
    const float* b_red = (const float*)d_in[2];
    const float* w3d   = (const float*)d_in[3];
    const float* b3d   = (const float*)d_in[4];
    const float* w2d   = (const float*)d_in[5];
    const float* b2d   = (const float*)d_in[6];
    float* out = (float*)d_out;

    char* ws = (char*)d_ws;
    u16*   hT16  = (u16*)(ws + 0);
    u16*   W3n   = (u16*)(ws + 65536);
    u16*   W2h   = (u16*)(ws + 4259840);
    float* c0    = (float*)(ws + 4390912);
    int*   tab   = (int*)(ws + 4391424);
    u16*   G     = (u16*)(ws + 9741312);
    u16*   m3T   = (u16*)(ws + 18129920);
    u16*   SMd   = (u16*)(ws + 35038208);

    setup_kernel<<<2834, 256, 0, stream>>>(x, w_red, b_red, w3d, w2d, b3d, b2d,
                                           W3n, hT16, W2h, tab, c0, SMd);
    gkern<<<256, 256, 0, stream>>>(W3n, hT16, G);
    mega_kernel<<<776, 256, 0, stream>>>(G, SMd, b3d, m3T, c0, out);
    gemm2f_kernel<<<258, 256, 0, stream>>>(m3T, W2h, b2d, tab, out);
}